// Round 3
// baseline (89.598 us; speedup 1.0000x reference)
//
#include <hip/hip_runtime.h>

#define L_TOTAL   32768
#define E_DIM     64
#define K_TOTAL   1024
#define NT_TOTAL  64                  // K_TOTAL / 16
#define OUT_STRIDE 2097152            // L_TOTAL * E_DIM
#define XPAD      68                  // fp32 x-tile LDS pitch (words)
#define BLK_ROWS  64                  // latents per block

typedef _Float16 half_t;
typedef _Float16 half8  __attribute__((ext_vector_type(8)));
typedef float    floatx4 __attribute__((ext_vector_type(4)));

// ---------------------------------------------------------------------------
// Single fused kernel: distances + argmin + epilogue, with ON-THE-FLY
// codebook conversion (no staging kernel, no device scratch).
//
// Grid 512 x 256: block = 4 waves over the SAME 64 latents (rt=4/wave);
// wave ks scans K-quarter [ks*256, +256) = 16 nt, rotated per block.
// Per nt, each lane loads the raw fp32 row chunk
//   e[nt*16 + (lane&15)][kt*32 + (lane>>4)*8 .. +8]   (4 x float4, 16 B each
// -- same load count as the old staged records, 4.0 KB/nt vs 4.25 KB), and
// converts to f16 hi/lo fragments in registers. The e-row norm is reduced
// in-wave (shfl_xor 16/32), duplicating the old record's broadcast value.
// emb (256 KB) is L2/L3-resident; conversion VALU (~66 ops/nt) hides under
// L2/MFMA (round-1 A/B showed large VALU headroom in this loop).
//
// Argmin key = e_norm - 2*dot (x-norm constant in k, dropped). The rotated
// nt sequence splits into two monotone-kg segments (t < 16-rot and
// t >= 16-rot); within each, strict '<' IS numpy first-occurrence. One
// (bH < bL) in-place merge (low-kg segment keeps ties) restores exact
// global first-occurrence.
// ---------------------------------------------------------------------------

#define MFMA16(Af, Bf, C) \
    C = __builtin_amdgcn_mfma_f32_16x16x32_f16(Af, Bf, C, 0, 0, 0)

// Load raw fp32 codebook chunk for one nt into 4 float4 registers.
#define LOAD_NT(r0, r1, r2, r3, NTv)                                          \
    {                                                                         \
        const float* src_ = emb + ((size_t)(NTv) * 16 + ln) * E_DIM + q * 8;  \
        r0 = *(const float4*)(src_);          /* kt0 cols q*8   .. +4 */      \
        r1 = *(const float4*)(src_ + 4);      /* kt0 cols q*8+4 .. +4 */      \
        r2 = *(const float4*)(src_ + 32);     /* kt1 cols 32+q*8      */      \
        r3 = *(const float4*)(src_ + 36);     /* kt1 cols 32+q*8+4    */      \
    }

// Convert + distances + segmented argmin update for one nt.
#define COMPUTE_NT(r0, r1, r2, r3, NTv, Tv)                                   \
    {                                                                         \
        const int kg_ = (NTv) * 16 + ln;                                      \
        float f0_[8] = {r0.x, r0.y, r0.z, r0.w, r1.x, r1.y, r1.z, r1.w};      \
        float f1_[8] = {r2.x, r2.y, r2.z, r2.w, r3.x, r3.y, r3.z, r3.w};      \
        half8 h0_, l0_, h1_, l1_;                                             \
        float sn_ = 0.f;                                                      \
        _Pragma("unroll")                                                     \
        for (int j = 0; j < 8; ++j) {                                         \
            half_t hh = (half_t)f0_[j];                                       \
            h0_[j] = hh;                                                      \
            l0_[j] = (half_t)(f0_[j] - (float)hh);                            \
            sn_ = fmaf(f0_[j], f0_[j], sn_);                                  \
        }                                                                     \
        _Pragma("unroll")                                                     \
        for (int j = 0; j < 8; ++j) {                                         \
            half_t hh = (half_t)f1_[j];                                       \
            h1_[j] = hh;                                                      \
            l1_[j] = (half_t)(f1_[j] - (float)hh);                            \
            sn_ = fmaf(f1_[j], f1_[j], sn_);                                  \
        }                                                                     \
        sn_ += __shfl_xor(sn_, 16, 64);                                       \
        sn_ += __shfl_xor(sn_, 32, 64);                                       \
        floatx4 kk_[4];                                                       \
        _Pragma("unroll")                                                     \
        for (int rt_ = 0; rt_ < 4; ++rt_) {                                   \
            floatx4 Ca = {0.f,0.f,0.f,0.f}, Cb = {0.f,0.f,0.f,0.f};           \
            MFMA16(A[rt_][0][0], h0_, Ca); MFMA16(A[rt_][1][0], h1_, Ca);     \
            MFMA16(A[rt_][0][1], h0_, Cb); MFMA16(A[rt_][1][1], h1_, Cb);     \
            MFMA16(A[rt_][0][0], l0_, Cb); MFMA16(A[rt_][1][0], l1_, Cb);     \
            _Pragma("unroll")                                                 \
            for (int r = 0; r < 4; ++r)                                       \
                kk_[rt_][r] = fmaf(-2.0f, Ca[r] + Cb[r], sn_);                \
        }                                                                     \
        if ((Tv) < c) {   /* wave-uniform branch: high-kg segment */          \
            _Pragma("unroll")                                                 \
            for (int rt_ = 0; rt_ < 4; ++rt_) {                               \
                _Pragma("unroll")                                             \
                for (int r = 0; r < 4; ++r)                                   \
                    if (kk_[rt_][r] < bH[rt_][r]) {                           \
                        bH[rt_][r] = kk_[rt_][r]; iH[rt_][r] = kg_;           \
                    }                                                         \
            }                                                                 \
        } else {          /* low-kg (wrapped) segment */                      \
            _Pragma("unroll")                                                 \
            for (int rt_ = 0; rt_ < 4; ++rt_) {                               \
                _Pragma("unroll")                                             \
                for (int r = 0; r < 4; ++r)                                   \
                    if (kk_[rt_][r] < bL[rt_][r]) {                           \
                        bL[rt_][r] = kk_[rt_][r]; iL[rt_][r] = kg_;           \
                    }                                                         \
            }                                                                 \
        }                                                                     \
    }

__global__ __launch_bounds__(256, 2)
void vq_fused_kernel(const float* __restrict__ x,
                     const float* __restrict__ emb,
                     float* __restrict__ out) {
    __shared__ float s_x[BLK_ROWS * XPAD];   // 17408 B fp32 x tile
    __shared__ float s_best[4][BLK_ROWS];
    __shared__ int   s_bidx[4][BLK_ROWS];
    __shared__ int   s_fin[BLK_ROWS];

    const int tid   = threadIdx.x;
    const int ks    = tid >> 6;        // K-split wave 0..3
    const int lane  = tid & 63;
    const int q     = lane >> 4;
    const int ln    = lane & 15;
    const int mbase = blockIdx.x * BLK_ROWS;
    const int rot   = blockIdx.x & 15;
    const int nt0   = ks * 16;
    const int c     = 16 - rot;        // segment boundary in t

    // ---- stage x tile: coalesced float4 -> padded LDS (4 per thread)
    {
        const float4* xg = (const float4*)(x + (size_t)mbase * E_DIM);
        #pragma unroll
        for (int i = 0; i < 4; ++i) {
            const int f   = i * 256 + tid;       // 0..1023 float4 of tile
            const int row = f >> 4;
            const int col = (f & 15) * 4;
            *(float4*)(&s_x[row * XPAD + col]) = xg[f];
        }
    }
    __syncthreads();

    // ---- A fragments (hi/lo) for the block's 64 latents (no x-norms needed)
    half8 A[4][2][2];                  // [rt][kt][hi/lo]  = 64 VGPRs
    #pragma unroll
    for (int rt = 0; rt < 4; ++rt) {
        const float* xr = &s_x[(rt * 16 + ln) * XPAD + q * 8];
        #pragma unroll
        for (int kt = 0; kt < 2; ++kt) {
            float4 v0 = *(const float4*)(xr + kt * 32);
            float4 v1 = *(const float4*)(xr + kt * 32 + 4);
            float f[8] = {v0.x, v0.y, v0.z, v0.w, v1.x, v1.y, v1.z, v1.w};
            #pragma unroll
            for (int j = 0; j < 8; ++j) {
                half_t hh = (half_t)f[j];
                half_t ll = (half_t)(f[j] - (float)hh);
                A[rt][kt][0][j] = hh;
                A[rt][kt][1][j] = ll;
            }
        }
    }

    // ---- two accumulator sets (per monotone segment), strict '<' only
    float bH[4][4], bL[4][4];
    int   iH[4][4], iL[4][4];
    #pragma unroll
    for (int rt = 0; rt < 4; ++rt)
        #pragma unroll
        for (int r = 0; r < 4; ++r) {
            bH[rt][r] = 3.402823466e+38f; iH[rt][r] = 0x7fffffff;
            bL[rt][r] = 3.402823466e+38f; iL[rt][r] = 0x7fffffff;
        }

    // ---- K loop: 16 nt, two-buffer register pipeline (one load in flight)
    float4 a0, a1, a2, a3;             // buffer A (raw fp32)
    float4 b0, b1, b2, b3;             // buffer B (raw fp32)
    int nt_a, nt_b;
    nt_a = nt0 + (rot & 15);
    LOAD_NT(a0, a1, a2, a3, nt_a);

    #pragma unroll 1
    for (int t = 0; t < 16; t += 2) {
        // prefetch t+1 into buffer B
        nt_b = nt0 + ((t + 1 + rot) & 15);
        LOAD_NT(b0, b1, b2, b3, nt_b);
        // compute buffer A (step t)
        COMPUTE_NT(a0, a1, a2, a3, nt_a, t);
        // prefetch t+2 into buffer A
        if (t + 2 < 16) {
            nt_a = nt0 + ((t + 2 + rot) & 15);
            LOAD_NT(a0, a1, a2, a3, nt_a);
        }
        // compute buffer B (step t+1)
        COMPUTE_NT(b0, b1, b2, b3, nt_b, t + 1);
    }

    // ---- merge segments in place: low-kg segment keeps ties (first occ.)
    #pragma unroll
    for (int rt = 0; rt < 4; ++rt)
        #pragma unroll
        for (int r = 0; r < 4; ++r)
            if (bH[rt][r] < bL[rt][r]) { bL[rt][r] = bH[rt][r]; iL[rt][r] = iH[rt][r]; }

    // ---- argmin across the 16 col-lanes of each quad (ties -> lower index)
    #pragma unroll
    for (int o = 1; o < 16; o <<= 1) {
        #pragma unroll
        for (int rt = 0; rt < 4; ++rt)
            #pragma unroll
            for (int r = 0; r < 4; ++r) {
                float ob = __shfl_xor(bL[rt][r], o, 64);
                int   oi = __shfl_xor(iL[rt][r], o, 64);
                if (ob < bL[rt][r] || (ob == bL[rt][r] && oi < iL[rt][r])) {
                    bL[rt][r] = ob; iL[rt][r] = oi;
                }
            }
    }
    if (ln == 0) {
        #pragma unroll
        for (int rt = 0; rt < 4; ++rt)
            #pragma unroll
            for (int r = 0; r < 4; ++r) {
                s_best[ks][rt * 16 + q * 4 + r] = bL[rt][r];
                s_bidx[ks][rt * 16 + q * 4 + r] = iL[rt][r];
            }
    }
    __syncthreads();

    // ---- merge the 4 K-splits (lexicographic == first-occurrence)
    if (tid < BLK_ROWS) {
        float b = 3.402823466e+38f;
        int   i = 0x7fffffff;
        #pragma unroll
        for (int s = 0; s < 4; ++s) {
            float pb = s_best[s][tid];
            int   pi = s_bidx[s][tid];
            if (pb < b || (pb == b && pi < i)) { b = pb; i = pi; }
        }
        s_fin[tid] = i;
        out[3 * (size_t)OUT_STRIDE + mbase + tid] = (float)i;   // coalesced
    }
    __syncthreads();

    // ---- coalesced epilogue over the 64x64 tile:
    // out0 = exact x (LDS), out1 = emb[idx], out2 = (x + q) - x.
    {
        const size_t fb = (size_t)mbase * (E_DIM / 4);
        float4* o0 = (float4*)out + fb;
        float4* o1 = (float4*)(out + OUT_STRIDE) + fb;
        float4* o2 = (float4*)(out + 2 * (size_t)OUT_STRIDE) + fb;
        #pragma unroll
        for (int i = 0; i < 4; ++i) {
            const int f   = i * 256 + tid;       // 0..1023
            const int row = f >> 4;
            const int col = (f & 15) * 4;
            const float4 xv = *(const float4*)(&s_x[row * XPAD + col]);
            const int idx = s_fin[row];
            const float4 qv = *(const float4*)(emb + (size_t)idx * E_DIM + col);
            float4 z;
            z.x = __fsub_rn(__fadd_rn(xv.x, qv.x), xv.x);
            z.y = __fsub_rn(__fadd_rn(xv.y, qv.y), xv.y);
            z.z = __fsub_rn(__fadd_rn(xv.z, qv.z), xv.z);
            z.w = __fsub_rn(__fadd_rn(xv.w, qv.w), xv.w);
            o0[f] = xv;
            o1[f] = qv;
            o2[f] = z;
        }
    }
}

// ---------------------------------------------------------------------------
extern "C" void kernel_launch(void* const* d_in, const int* in_sizes, int n_in,
                              void* d_out, int out_size, void* d_ws, size_t ws_size,
                              hipStream_t stream) {
    const float* x   = (const float*)d_in[0];
    const float* emb = (const float*)d_in[1];
    float* out  = (float*)d_out;
    (void)d_ws; (void)ws_size;   // workspace deliberately unused

    hipLaunchKernelGGL(vq_fused_kernel, dim3(L_TOTAL / BLK_ROWS), dim3(256), 0, stream,
                       x, emb, out);
}

// Round 4
// 85.651 us; speedup vs baseline: 1.0461x; 1.0461x over previous
//
#include <hip/hip_runtime.h>

#define L_TOTAL   32768
#define E_DIM     64
#define K_TOTAL   1024
#define NT_TOTAL  64                  // K_TOTAL / 16
#define OUT_STRIDE 2097152            // L_TOTAL * E_DIM
#define XPAD      68                  // fp32 x-tile LDS pitch (words)
#define BLK_ROWS  64                  // latents per block

// staging record: per nt = 1280 words (5120 B):
//   [0,256)    kt0 hi frags (64 lanes x 16 B)
//   [256,512)  kt1 hi
//   [512,768)  kt0 lo
//   [768,1024) kt1 lo
//   [1024,1088) norms (64 f32, dup x4 over quads)
//   [1088,1280) pad
#define NT_WORDS  1280

typedef _Float16 half_t;
typedef _Float16 half8  __attribute__((ext_vector_type(8)));
typedef float    floatx4 __attribute__((ext_vector_type(4)));

// Staged codebook in module device memory. Recomputed from emb every launch
// (no cross-iteration state). Round-3 A/B proved staging beats on-the-fly
// conversion by ~3 us (512x redundant convert VALU + strided raw gather).
__device__ float g_ebuf[NT_TOTAL * NT_WORDS];   // 320 KB

// ---------------------------------------------------------------------------
// Codebook fp32 -> staged records (f16 hi/lo fragments + norms).
// Fragment (nt,kt,lane) = e[nt*16 + (lane&15)][kt*32 + (lane>>4)*8 .. +8].
// ---------------------------------------------------------------------------
__global__ __launch_bounds__(128)
void vq_swizzle_kernel(const float* __restrict__ emb) {
    __shared__ float s_p[128];
    __shared__ float s_n[16];
    const int nt   = blockIdx.x;
    const int t    = threadIdx.x;
    const int kt   = t >> 6;
    const int lane = t & 63;
    const int q    = lane >> 4;
    const int ln   = lane & 15;

    const float* src = emb + (size_t)(nt * 16 + ln) * E_DIM + kt * 32 + q * 8;
    float4 v0 = *(const float4*)src;
    float4 v1 = *(const float4*)(src + 4);
    float f[8] = {v0.x, v0.y, v0.z, v0.w, v1.x, v1.y, v1.z, v1.w};

    half8 h, l;
    float s = 0.f;
    #pragma unroll
    for (int j = 0; j < 8; ++j) {
        half_t hh = (half_t)f[j];
        half_t ll = (half_t)(f[j] - (float)hh);
        h[j] = hh;
        l[j] = ll;
        s = fmaf(f[j], f[j], s);
    }
    float* rec = g_ebuf + (size_t)nt * NT_WORDS;
    *(half8*)(rec + kt * 256 + lane * 4)       = h;   // hi
    *(half8*)(rec + 512 + kt * 256 + lane * 4) = l;   // lo

    s_p[t] = s;
    __syncthreads();
    if (t < 16) {
        float n = 0.f;
        #pragma unroll
        for (int u = 0; u < 8; ++u)
            n += s_p[(u >> 2) * 64 + (u & 3) * 16 + t];
        s_n[t] = n;
    }
    __syncthreads();
    if (t < 64) rec[1024 + t] = s_n[t & 15];
}

// ---------------------------------------------------------------------------
// Fused distances + argmin + epilogue.
// Grid 512 x 256: block = 4 waves over the SAME 64 latents (rt=4/wave);
// wave ks scans K-quarter [ks*256, +256) = 16 nt, rotated per block.
//
// Argmin key = e_norm - 2*dot (x-norm constant in k, dropped). The rotated
// nt sequence splits into two monotone-kg segments (t < 16-rot and
// t >= 16-rot); within each, strict '<' IS numpy first-occurrence. One
// (bH < bL) in-place merge (low-kg segment keeps ties) restores exact
// global first-occurrence.
//
// out0 = x is stored DURING the staging loop (value already in registers,
// independent of argmin) so 8.4 MB of write traffic drains under the K-loop
// instead of serializing in the epilogue tail.
// ---------------------------------------------------------------------------

#define MFMA16(Af, Bf, C) \
    C = __builtin_amdgcn_mfma_f32_16x16x32_f16(Af, Bf, C, 0, 0, 0)

// Distances + segmented argmin update for one nt (register buffer r0..r3,rn).
#define COMPUTE_NT(r0, r1, r2, r3, rn, NTv, Tv)                               \
    {                                                                         \
        const int kg_ = (NTv) * 16 + ln;                                      \
        floatx4 kk_[4];                                                       \
        _Pragma("unroll")                                                     \
        for (int rt_ = 0; rt_ < 4; ++rt_) {                                   \
            floatx4 Ca = {0.f,0.f,0.f,0.f}, Cb = {0.f,0.f,0.f,0.f};           \
            MFMA16(A[rt_][0][0], r0, Ca); MFMA16(A[rt_][1][0], r1, Ca);       \
            MFMA16(A[rt_][0][1], r0, Cb); MFMA16(A[rt_][1][1], r1, Cb);       \
            MFMA16(A[rt_][0][0], r2, Cb); MFMA16(A[rt_][1][0], r3, Cb);       \
            _Pragma("unroll")                                                 \
            for (int r = 0; r < 4; ++r)                                       \
                kk_[rt_][r] = fmaf(-2.0f, Ca[r] + Cb[r], rn);                 \
        }                                                                     \
        if ((Tv) < c) {   /* wave-uniform branch: high-kg segment */          \
            _Pragma("unroll")                                                 \
            for (int rt_ = 0; rt_ < 4; ++rt_) {                               \
                _Pragma("unroll")                                             \
                for (int r = 0; r < 4; ++r)                                   \
                    if (kk_[rt_][r] < bH[rt_][r]) {                           \
                        bH[rt_][r] = kk_[rt_][r]; iH[rt_][r] = kg_;           \
                    }                                                         \
            }                                                                 \
        } else {          /* low-kg (wrapped) segment */                      \
            _Pragma("unroll")                                                 \
            for (int rt_ = 0; rt_ < 4; ++rt_) {                               \
                _Pragma("unroll")                                             \
                for (int r = 0; r < 4; ++r)                                   \
                    if (kk_[rt_][r] < bL[rt_][r]) {                           \
                        bL[rt_][r] = kk_[rt_][r]; iL[rt_][r] = kg_;           \
                    }                                                         \
            }                                                                 \
        }                                                                     \
    }

__global__ __launch_bounds__(256, 2)
void vq_fused_kernel(const float* __restrict__ x,
                     const float* __restrict__ emb,
                     float* __restrict__ out) {
    __shared__ float s_x[BLK_ROWS * XPAD];   // 17408 B fp32 x tile
    __shared__ float s_best[4][BLK_ROWS];
    __shared__ int   s_bidx[4][BLK_ROWS];
    __shared__ int   s_fin[BLK_ROWS];

    const int tid   = threadIdx.x;
    const int ks    = tid >> 6;        // K-split wave 0..3
    const int lane  = tid & 63;
    const int q     = lane >> 4;
    const int ln    = lane & 15;
    const int mbase = blockIdx.x * BLK_ROWS;
    const int rot   = blockIdx.x & 15;
    const int nt0   = ks * 16;
    const int c     = 16 - rot;        // segment boundary in t

    // ---- stage x tile: coalesced float4 -> padded LDS (4 per thread),
    //      and store out0 = x immediately (overlaps with the whole K-loop)
    {
        const float4* xg = (const float4*)(x + (size_t)mbase * E_DIM);
        float4* o0 = (float4*)out + (size_t)mbase * (E_DIM / 4);
        #pragma unroll
        for (int i = 0; i < 4; ++i) {
            const int f   = i * 256 + tid;       // 0..1023 float4 of tile
            const int row = f >> 4;
            const int col = (f & 15) * 4;
            const float4 xv = xg[f];
            *(float4*)(&s_x[row * XPAD + col]) = xv;
            o0[f] = xv;
        }
    }
    __syncthreads();

    // ---- A fragments (hi/lo) for the block's 64 latents (no x-norms needed)
    half8 A[4][2][2];                  // [rt][kt][hi/lo]  = 64 VGPRs
    #pragma unroll
    for (int rt = 0; rt < 4; ++rt) {
        const float* xr = &s_x[(rt * 16 + ln) * XPAD + q * 8];
        #pragma unroll
        for (int kt = 0; kt < 2; ++kt) {
            float4 v0 = *(const float4*)(xr + kt * 32);
            float4 v1 = *(const float4*)(xr + kt * 32 + 4);
            float f[8] = {v0.x, v0.y, v0.z, v0.w, v1.x, v1.y, v1.z, v1.w};
            #pragma unroll
            for (int j = 0; j < 8; ++j) {
                half_t hh = (half_t)f[j];
                half_t ll = (half_t)(f[j] - (float)hh);
                A[rt][kt][0][j] = hh;
                A[rt][kt][1][j] = ll;
            }
        }
    }

    // ---- two accumulator sets (per monotone segment), strict '<' only
    float bH[4][4], bL[4][4];
    int   iH[4][4], iL[4][4];
    #pragma unroll
    for (int rt = 0; rt < 4; ++rt)
        #pragma unroll
        for (int r = 0; r < 4; ++r) {
            bH[rt][r] = 3.402823466e+38f; iH[rt][r] = 0x7fffffff;
            bL[rt][r] = 3.402823466e+38f; iL[rt][r] = 0x7fffffff;
        }

    // ---- K loop: 16 nt, two-buffer register pipeline (one load in flight)
    half8 a0, a1, a2, a3; float ae;    // buffer A
    half8 b0, b1, b2, b3; float be;    // buffer B
    int nt_a, nt_b;
    {
        nt_a = nt0 + (rot & 15);
        const float* rec = g_ebuf + (size_t)nt_a * NT_WORDS;
        a0 = *(const half8*)(rec + lane * 4);
        a1 = *(const half8*)(rec + 256 + lane * 4);
        a2 = *(const half8*)(rec + 512 + lane * 4);
        a3 = *(const half8*)(rec + 768 + lane * 4);
        ae = rec[1024 + lane];
    }

    #pragma unroll 1
    for (int t = 0; t < 16; t += 2) {
        // prefetch t+1 into buffer B
        nt_b = nt0 + ((t + 1 + rot) & 15);
        {
            const float* rec = g_ebuf + (size_t)nt_b * NT_WORDS;
            b0 = *(const half8*)(rec + lane * 4);
            b1 = *(const half8*)(rec + 256 + lane * 4);
            b2 = *(const half8*)(rec + 512 + lane * 4);
            b3 = *(const half8*)(rec + 768 + lane * 4);
            be = rec[1024 + lane];
        }
        // compute buffer A (step t)
        COMPUTE_NT(a0, a1, a2, a3, ae, nt_a, t);
        // prefetch t+2 into buffer A
        if (t + 2 < 16) {
            nt_a = nt0 + ((t + 2 + rot) & 15);
            const float* rec = g_ebuf + (size_t)nt_a * NT_WORDS;
            a0 = *(const half8*)(rec + lane * 4);
            a1 = *(const half8*)(rec + 256 + lane * 4);
            a2 = *(const half8*)(rec + 512 + lane * 4);
            a3 = *(const half8*)(rec + 768 + lane * 4);
            ae = rec[1024 + lane];
        }
        // compute buffer B (step t+1)
        COMPUTE_NT(b0, b1, b2, b3, be, nt_b, t + 1);
    }

    // ---- merge segments in place: low-kg segment keeps ties (first occ.)
    #pragma unroll
    for (int rt = 0; rt < 4; ++rt)
        #pragma unroll
        for (int r = 0; r < 4; ++r)
            if (bH[rt][r] < bL[rt][r]) { bL[rt][r] = bH[rt][r]; iL[rt][r] = iH[rt][r]; }

    // ---- argmin across the 16 col-lanes of each quad (ties -> lower index)
    #pragma unroll
    for (int o = 1; o < 16; o <<= 1) {
        #pragma unroll
        for (int rt = 0; rt < 4; ++rt)
            #pragma unroll
            for (int r = 0; r < 4; ++r) {
                float ob = __shfl_xor(bL[rt][r], o, 64);
                int   oi = __shfl_xor(iL[rt][r], o, 64);
                if (ob < bL[rt][r] || (ob == bL[rt][r] && oi < iL[rt][r])) {
                    bL[rt][r] = ob; iL[rt][r] = oi;
                }
            }
    }
    if (ln == 0) {
        #pragma unroll
        for (int rt = 0; rt < 4; ++rt)
            #pragma unroll
            for (int r = 0; r < 4; ++r) {
                s_best[ks][rt * 16 + q * 4 + r] = bL[rt][r];
                s_bidx[ks][rt * 16 + q * 4 + r] = iL[rt][r];
            }
    }
    __syncthreads();

    // ---- merge the 4 K-splits (lexicographic == first-occurrence)
    if (tid < BLK_ROWS) {
        float b = 3.402823466e+38f;
        int   i = 0x7fffffff;
        #pragma unroll
        for (int s = 0; s < 4; ++s) {
            float pb = s_best[s][tid];
            int   pi = s_bidx[s][tid];
            if (pb < b || (pb == b && pi < i)) { b = pb; i = pi; }
        }
        s_fin[tid] = i;
        out[3 * (size_t)OUT_STRIDE + mbase + tid] = (float)i;   // coalesced
    }
    __syncthreads();

    // ---- coalesced epilogue over the 64x64 tile:
    // out1 = emb[idx], out2 = (x + q) - x.  (out0 already stored above.)
    {
        const size_t fb = (size_t)mbase * (E_DIM / 4);
        float4* o1 = (float4*)(out + OUT_STRIDE) + fb;
        float4* o2 = (float4*)(out + 2 * (size_t)OUT_STRIDE) + fb;
        #pragma unroll
        for (int i = 0; i < 4; ++i) {
            const int f   = i * 256 + tid;       // 0..1023
            const int row = f >> 4;
            const int col = (f & 15) * 4;
            const float4 xv = *(const float4*)(&s_x[row * XPAD + col]);
            const int idx = s_fin[row];
            const float4 qv = *(const float4*)(emb + (size_t)idx * E_DIM + col);
            float4 z;
            z.x = __fsub_rn(__fadd_rn(xv.x, qv.x), xv.x);
            z.y = __fsub_rn(__fadd_rn(xv.y, qv.y), xv.y);
            z.z = __fsub_rn(__fadd_rn(xv.z, qv.z), xv.z);
            z.w = __fsub_rn(__fadd_rn(xv.w, qv.w), xv.w);
            o1[f] = qv;
            o2[f] = z;
        }
    }
}

// ---------------------------------------------------------------------------
extern "C" void kernel_launch(void* const* d_in, const int* in_sizes, int n_in,
                              void* d_out, int out_size, void* d_ws, size_t ws_size,
                              hipStream_t stream) {
    const float* x   = (const float*)d_in[0];
    const float* emb = (const float*)d_in[1];
    float* out  = (float*)d_out;
    (void)d_ws; (void)ws_size;   // workspace deliberately unused

    hipLaunchKernelGGL(vq_swizzle_kernel, dim3(NT_TOTAL), dim3(128), 0, stream,
                       emb);
    hipLaunchKernelGGL(vq_fused_kernel, dim3(L_TOTAL / BLK_ROWS), dim3(256), 0, stream,
                       x, emb, out);
}